// Round 3
// baseline (722.007 us; speedup 1.0000x reference)
//
#include <hip/hip_runtime.h>
#include <hip/hip_bf16.h>

#define NN 50000
#define EE 800000
#define ET (EE + NN)   // edges + self loops = 850000
#define CC 64
#define HH 2
#define LL 3
#define SCAN_CHUNK 1024

// ---------------- CSR construction ----------------

__global__ void k_zero(int* p, int n) {
    int i = blockIdx.x * blockDim.x + threadIdx.x;
    if (i < n) p[i] = 0;
}

// count in-degree into rowstart[dst+1]
__global__ void k_deg(const int* __restrict__ ei, int* __restrict__ cnt1, int etot) {
    int e = blockIdx.x * blockDim.x + threadIdx.x;
    if (e < etot) {
        int d = (e < EE) ? ei[EE + e] : (e - EE);
        atomicAdd(&cnt1[d + 1], 1);
    }
}

// inclusive scan, 3-phase
__global__ __launch_bounds__(SCAN_CHUNK) void k_scan1(int* __restrict__ data,
                                                      int* __restrict__ bsums, int n) {
    __shared__ int tmp[SCAN_CHUNK];
    int i = blockIdx.x * SCAN_CHUNK + threadIdx.x;
    int v = (i < n) ? data[i] : 0;
    tmp[threadIdx.x] = v;
    __syncthreads();
    for (int off = 1; off < SCAN_CHUNK; off <<= 1) {
        int t = (threadIdx.x >= off) ? tmp[threadIdx.x - off] : 0;
        __syncthreads();
        tmp[threadIdx.x] += t;
        __syncthreads();
    }
    if (i < n) data[i] = tmp[threadIdx.x];
    if (threadIdx.x == SCAN_CHUNK - 1) bsums[blockIdx.x] = tmp[SCAN_CHUNK - 1];
}

__global__ void k_scan2(int* bsums, int nb) {
    if (blockIdx.x == 0 && threadIdx.x == 0) {
        int run = 0;
        for (int b = 0; b < nb; b++) { int t = bsums[b]; bsums[b] = run; run += t; }
    }
}

__global__ __launch_bounds__(SCAN_CHUNK) void k_scan3(int* __restrict__ data,
                                                      const int* __restrict__ bsums, int n) {
    int i = blockIdx.x * SCAN_CHUNK + threadIdx.x;
    if (i < n) data[i] += bsums[blockIdx.x];
}

__global__ void k_copy(const int* __restrict__ a, int* __restrict__ b, int n) {
    int i = blockIdx.x * blockDim.x + threadIdx.x;
    if (i < n) b[i] = a[i];
}

__global__ void k_scatter(const int* __restrict__ ei, int* __restrict__ cursor,
                          int* __restrict__ src_csr, int* __restrict__ dst_csr, int etot) {
    int e = blockIdx.x * blockDim.x + threadIdx.x;
    if (e < etot) {
        int s, d;
        if (e < EE) { s = ei[e]; d = ei[EE + e]; } else { s = d = e - EE; }
        int pos = atomicAdd(&cursor[d], 1);
        src_csr[pos] = s;
        dst_csr[pos] = d;
    }
}

// ---------------- feature init ----------------

__global__ void k_init(const float* __restrict__ x, float* __restrict__ hA,
                       float* __restrict__ acc, int n) {
    int i = blockIdx.x * blockDim.x + threadIdx.x;
    if (i < n) {
        float v = x[i];
        hA[i] = v;
        acc[i] = 0.25f * v;   // acc == d_out (fp32), feats-mean fused
    }
}

// ---------------- per-layer: alpha (wave per edge) ----------------

__global__ __launch_bounds__(256) void k_alpha(const float* __restrict__ h,
                                               const int* __restrict__ src_csr,
                                               const int* __restrict__ dst_csr,
                                               const float* __restrict__ att_l,
                                               float* __restrict__ alpha, int etot) {
    int gid = blockIdx.x * blockDim.x + threadIdx.x;
    int e = gid >> 6;
    int lane = threadIdx.x & 63;
    if (e >= etot) return;
    float a0c = att_l[lane];
    float a1c = att_l[CC + lane];
    int s = src_csr[e], d = dst_csr[e];
    float v = h[d * CC + lane] + h[s * CC + lane];
    float lr = fmaxf(v, 0.f) + 0.2f * fminf(v, 0.f);   // leaky_relu slope 0.2
    float a0 = lr * a0c;
    float a1 = lr * a1c;
#pragma unroll
    for (int m = 32; m; m >>= 1) {
        a0 += __shfl_xor(a0, m);
        a1 += __shfl_xor(a1, m);
    }
    if (lane == 0) ((float2*)alpha)[e] = make_float2(a0, a1);
}

// ---------------- per-layer: softmax + aggregate (wave per node) ----------------

__global__ __launch_bounds__(256) void k_agg(const float* __restrict__ h,
                                             const int* __restrict__ rowstart,
                                             const int* __restrict__ src_csr,
                                             const float* __restrict__ alpha,
                                             const float* __restrict__ bias_l,
                                             float* __restrict__ h_out,
                                             float* __restrict__ acc, int n) {
    __shared__ float e0s[4][128];
    __shared__ float e1s[4][128];
    int wid = threadIdx.x >> 6;
    int lane = threadIdx.x & 63;
    int node = blockIdx.x * 4 + wid;
    if (node >= n) return;
    int rs = rowstart[node];
    int d = rowstart[node + 1] - rs;

    // phase A: lanes over edges — segment max, exp-sum
    float m0 = -1e30f, m1 = -1e30f;
    for (int i = lane; i < d; i += 64) {
        float2 a = ((const float2*)alpha)[rs + i];
        m0 = fmaxf(m0, a.x);
        m1 = fmaxf(m1, a.y);
    }
#pragma unroll
    for (int m = 32; m; m >>= 1) {
        m0 = fmaxf(m0, __shfl_xor(m0, m));
        m1 = fmaxf(m1, __shfl_xor(m1, m));
    }
    bool fits = (d <= 128);
    float s0 = 0.f, s1 = 0.f;
    for (int i = lane; i < d; i += 64) {
        float2 a = ((const float2*)alpha)[rs + i];
        float e0 = __expf(a.x - m0);
        float e1 = __expf(a.y - m1);
        if (fits) { e0s[wid][i] = e0; e1s[wid][i] = e1; }
        s0 += e0;
        s1 += e1;
    }
#pragma unroll
    for (int m = 32; m; m >>= 1) {
        s0 += __shfl_xor(s0, m);
        s1 += __shfl_xor(s1, m);
    }
    float inv0 = 0.5f / (s0 + 1e-16f);   // fold mean-over-heads into 1/s
    float inv1 = 0.5f / (s1 + 1e-16f);

    // phase B: lanes over channels — weighted gather of source rows
    float accv = 0.f;
    if (fits) {
        for (int i = 0; i < d; i++) {
            float w = e0s[wid][i] * inv0 + e1s[wid][i] * inv1;
            int s = src_csr[rs + i];
            accv += w * h[s * CC + lane];
        }
    } else {
        for (int i = 0; i < d; i++) {
            float2 a = ((const float2*)alpha)[rs + i];
            float w = __expf(a.x - m0) * inv0 + __expf(a.y - m1) * inv1;
            int s = src_csr[rs + i];
            accv += w * h[s * CC + lane];
        }
    }
    float outv = accv + bias_l[lane];
    h_out[node * CC + lane] = outv;
    acc[node * CC + lane] += 0.25f * outv;
}

// ---------------- launch ----------------

static inline size_t align256(size_t x) { return (x + 255) & ~(size_t)255; }

extern "C" void kernel_launch(void* const* d_in, const int* in_sizes, int n_in,
                              void* d_out, int out_size, void* d_ws, size_t ws_size,
                              hipStream_t stream) {
    const float* x    = (const float*)d_in[0];
    const int*   ei   = (const int*)d_in[1];
    const float* att  = (const float*)d_in[2];
    const float* bias = (const float*)d_in[3];
    float* acc = (float*)d_out;   // fp32 output; feats-mean accumulated here

    char* w = (char*)d_ws;
    int* rowstart = (int*)w;            w += align256((NN + 1) * sizeof(int));
    int* cursor   = (int*)w;            w += align256(NN * sizeof(int));
    int* bsums    = (int*)w;            w += align256(256 * sizeof(int));
    int* src_csr  = (int*)w;            w += align256((size_t)ET * sizeof(int));
    int* dst_csr  = (int*)w;            w += align256((size_t)ET * sizeof(int));
    float* alpha  = (float*)w;          w += align256((size_t)ET * 2 * sizeof(float));
    float* hA     = (float*)w;          w += align256((size_t)NN * CC * sizeof(float));
    float* hB     = (float*)w;          w += align256((size_t)NN * CC * sizeof(float));

    const int B = 256;
    int nscan = NN + 1;
    int nb = (nscan + SCAN_CHUNK - 1) / SCAN_CHUNK;

    // CSR build (per call; ws is re-poisoned before every launch)
    k_zero<<<(nscan + B - 1) / B, B, 0, stream>>>(rowstart, nscan);
    k_deg<<<(ET + B - 1) / B, B, 0, stream>>>(ei, rowstart, ET);
    k_scan1<<<nb, SCAN_CHUNK, 0, stream>>>(rowstart, bsums, nscan);
    k_scan2<<<1, 64, 0, stream>>>(bsums, nb);
    k_scan3<<<nb, SCAN_CHUNK, 0, stream>>>(rowstart, bsums, nscan);
    k_copy<<<(NN + B - 1) / B, B, 0, stream>>>(rowstart, cursor, NN);
    k_scatter<<<(ET + B - 1) / B, B, 0, stream>>>(ei, cursor, src_csr, dst_csr, ET);

    // features (also initializes d_out = 0.25*x)
    k_init<<<(NN * CC + B - 1) / B, B, 0, stream>>>(x, hA, acc, NN * CC);

    float* hin = hA;
    float* hout = hB;
    for (int l = 0; l < LL; l++) {
        k_alpha<<<((size_t)ET * 64 + B - 1) / B, B, 0, stream>>>(
            hin, src_csr, dst_csr, att + (size_t)l * HH * CC, alpha, ET);
        k_agg<<<(NN + 3) / 4, B, 0, stream>>>(
            hin, rowstart, src_csr, alpha, bias + (size_t)l * CC, hout, acc, NN);
        float* t = hin; hin = hout; hout = t;
    }
}

// Round 4
// 428.342 us; speedup vs baseline: 1.6856x; 1.6856x over previous
//
#include <hip/hip_runtime.h>
#include <hip/hip_bf16.h>

#define NN 50000
#define EE 800000
#define ET (EE + NN)   // edges + self loops = 850000
#define CC 64
#define HH 2
#define LL 3
#define SCAN_CHUNK 1024

// ---------------- CSR construction ----------------

__global__ void k_zero(int* p, int n) {
    int i = blockIdx.x * blockDim.x + threadIdx.x;
    if (i < n) p[i] = 0;
}

__global__ void k_deg(const int* __restrict__ ei, int* __restrict__ cnt1, int etot) {
    int e = blockIdx.x * blockDim.x + threadIdx.x;
    if (e < etot) {
        int d = (e < EE) ? ei[EE + e] : (e - EE);
        atomicAdd(&cnt1[d + 1], 1);
    }
}

__global__ __launch_bounds__(SCAN_CHUNK) void k_scan1(int* __restrict__ data,
                                                      int* __restrict__ bsums, int n) {
    __shared__ int tmp[SCAN_CHUNK];
    int i = blockIdx.x * SCAN_CHUNK + threadIdx.x;
    int v = (i < n) ? data[i] : 0;
    tmp[threadIdx.x] = v;
    __syncthreads();
    for (int off = 1; off < SCAN_CHUNK; off <<= 1) {
        int t = (threadIdx.x >= off) ? tmp[threadIdx.x - off] : 0;
        __syncthreads();
        tmp[threadIdx.x] += t;
        __syncthreads();
    }
    if (i < n) data[i] = tmp[threadIdx.x];
    if (threadIdx.x == SCAN_CHUNK - 1) bsums[blockIdx.x] = tmp[SCAN_CHUNK - 1];
}

__global__ void k_scan2(int* bsums, int nb) {
    if (blockIdx.x == 0 && threadIdx.x == 0) {
        int run = 0;
        for (int b = 0; b < nb; b++) { int t = bsums[b]; bsums[b] = run; run += t; }
    }
}

__global__ __launch_bounds__(SCAN_CHUNK) void k_scan3(int* __restrict__ data,
                                                      const int* __restrict__ bsums, int n) {
    int i = blockIdx.x * SCAN_CHUNK + threadIdx.x;
    if (i < n) data[i] += bsums[blockIdx.x];
}

__global__ void k_copy(const int* __restrict__ a, int* __restrict__ b, int n) {
    int i = blockIdx.x * blockDim.x + threadIdx.x;
    if (i < n) b[i] = a[i];
}

__global__ void k_scatter(const int* __restrict__ ei, int* __restrict__ cursor,
                          int* __restrict__ src_csr, int* __restrict__ dst_csr, int etot) {
    int e = blockIdx.x * blockDim.x + threadIdx.x;
    if (e < etot) {
        int s, d;
        if (e < EE) { s = ei[e]; d = ei[EE + e]; } else { s = d = e - EE; }
        int pos = atomicAdd(&cursor[d], 1);
        src_csr[pos] = s;
        dst_csr[pos] = d;
    }
}

// ---------------- feature init ----------------

__global__ void k_init(const float* __restrict__ x, float* __restrict__ hA,
                       float* __restrict__ acc, int n) {
    int i = blockIdx.x * blockDim.x + threadIdx.x;
    if (i < n) {
        float v = x[i];
        hA[i] = v;
        acc[i] = 0.25f * v;   // acc == d_out (fp32), feats-mean fused
    }
}

// ---------------- per-layer: alpha (16 lanes per edge, float4 channels) ----------------

__global__ __launch_bounds__(256) void k_alpha(const float* __restrict__ h,
                                               const int* __restrict__ src_csr,
                                               const int* __restrict__ dst_csr,
                                               const float* __restrict__ att_l,
                                               float* __restrict__ alpha, int etot) {
    int lane = threadIdx.x & 63;
    int q = lane & 15;                                  // channel quad: c = 4q..4q+3
    int e = (int)((blockIdx.x * 256u + threadIdx.x) >> 4);
    if (e >= etot) return;
    const float4* h4 = (const float4*)h;
    float4 a0q = ((const float4*)att_l)[q];
    float4 a1q = ((const float4*)att_l)[16 + q];
    int s = src_csr[e], d = dst_csr[e];
    float4 vs = h4[(size_t)s * 16 + q];
    float4 vd = h4[(size_t)d * 16 + q];
    float vx = vs.x + vd.x, vy = vs.y + vd.y, vz = vs.z + vd.z, vw = vs.w + vd.w;
    vx = fmaxf(vx, 0.f) + 0.2f * fminf(vx, 0.f);
    vy = fmaxf(vy, 0.f) + 0.2f * fminf(vy, 0.f);
    vz = fmaxf(vz, 0.f) + 0.2f * fminf(vz, 0.f);
    vw = fmaxf(vw, 0.f) + 0.2f * fminf(vw, 0.f);
    float a0 = vx * a0q.x + vy * a0q.y + vz * a0q.z + vw * a0q.w;
    float a1 = vx * a1q.x + vy * a1q.y + vz * a1q.z + vw * a1q.w;
#pragma unroll
    for (int m = 8; m; m >>= 1) {                       // reduce within 16-lane group
        a0 += __shfl_xor(a0, m);
        a1 += __shfl_xor(a1, m);
    }
    if (q == 0) ((float2*)alpha)[e] = make_float2(a0, a1);
}

// ---------------- per-layer: softmax + aggregate (wave per node) ----------------

__global__ __launch_bounds__(256) void k_agg(const float* __restrict__ h,
                                             const int* __restrict__ rowstart,
                                             const int* __restrict__ src_csr,
                                             const float* __restrict__ alpha,
                                             const float* __restrict__ bias_l,
                                             float* __restrict__ h_out,
                                             float* __restrict__ acc, int n) {
    __shared__ float e0s[4][128];
    __shared__ float e1s[4][128];
    __shared__ float wsh[4][128];
    int wid = threadIdx.x >> 6;
    int lane = threadIdx.x & 63;
    int node = blockIdx.x * 4 + wid;
    if (node >= n) return;
    int rs = rowstart[node];
    int d = rowstart[node + 1] - rs;

    // phase A: lanes over edges — segment max, exp-sum
    float m0 = -1e30f, m1 = -1e30f;
    for (int i = lane; i < d; i += 64) {
        float2 a = ((const float2*)alpha)[rs + i];
        m0 = fmaxf(m0, a.x);
        m1 = fmaxf(m1, a.y);
    }
#pragma unroll
    for (int m = 32; m; m >>= 1) {
        m0 = fmaxf(m0, __shfl_xor(m0, m));
        m1 = fmaxf(m1, __shfl_xor(m1, m));
    }
    bool fits = (d <= 128);
    float s0 = 0.f, s1 = 0.f;
    for (int i = lane; i < d; i += 64) {
        float2 a = ((const float2*)alpha)[rs + i];
        float e0 = __expf(a.x - m0);
        float e1 = __expf(a.y - m1);
        if (fits) { e0s[wid][i] = e0; e1s[wid][i] = e1; }
        s0 += e0;
        s1 += e1;
    }
#pragma unroll
    for (int m = 32; m; m >>= 1) {
        s0 += __shfl_xor(s0, m);
        s1 += __shfl_xor(s1, m);
    }
    float inv0 = 0.5f / (s0 + 1e-16f);   // fold mean-over-heads into 1/s
    float inv1 = 0.5f / (s1 + 1e-16f);

    if (fits) {
        for (int i = lane; i < d; i += 64)
            wsh[wid][i] = e0s[wid][i] * inv0 + e1s[wid][i] * inv1;
    }

    // phase B: 4 subgroups of 16 lanes; each subgroup strides edges; float4 channels
    int sub = lane >> 4, q = lane & 15;
    const float4* h4 = (const float4*)h;
    float ax = 0.f, ay = 0.f, az = 0.f, aw = 0.f;
    if (fits) {
        for (int i = sub; i < d; i += 4) {
            float w = wsh[wid][i];
            int s = src_csr[rs + i];
            float4 hv = h4[(size_t)s * 16 + q];
            ax += w * hv.x; ay += w * hv.y; az += w * hv.z; aw += w * hv.w;
        }
    } else {
        for (int i = sub; i < d; i += 4) {
            float2 a = ((const float2*)alpha)[rs + i];
            float w = __expf(a.x - m0) * inv0 + __expf(a.y - m1) * inv1;
            int s = src_csr[rs + i];
            float4 hv = h4[(size_t)s * 16 + q];
            ax += w * hv.x; ay += w * hv.y; az += w * hv.z; aw += w * hv.w;
        }
    }
#pragma unroll
    for (int m = 16; m <= 32; m <<= 1) {
        ax += __shfl_xor(ax, m);
        ay += __shfl_xor(ay, m);
        az += __shfl_xor(az, m);
        aw += __shfl_xor(aw, m);
    }
    if (sub == 0) {
        float4 b4 = ((const float4*)bias_l)[q];
        float4 o;
        o.x = ax + b4.x; o.y = ay + b4.y; o.z = az + b4.z; o.w = aw + b4.w;
        ((float4*)h_out)[(size_t)node * 16 + q] = o;
        float4* accp = (float4*)acc + (size_t)node * 16 + q;
        float4 ac = *accp;
        ac.x += 0.25f * o.x; ac.y += 0.25f * o.y;
        ac.z += 0.25f * o.z; ac.w += 0.25f * o.w;
        *accp = ac;
    }
}

// ---------------- launch ----------------

static inline size_t align256(size_t x) { return (x + 255) & ~(size_t)255; }

extern "C" void kernel_launch(void* const* d_in, const int* in_sizes, int n_in,
                              void* d_out, int out_size, void* d_ws, size_t ws_size,
                              hipStream_t stream) {
    const float* x    = (const float*)d_in[0];
    const int*   ei   = (const int*)d_in[1];
    const float* att  = (const float*)d_in[2];
    const float* bias = (const float*)d_in[3];
    float* acc = (float*)d_out;   // fp32 output; feats-mean accumulated here

    char* w = (char*)d_ws;
    int* rowstart = (int*)w;            w += align256((NN + 1) * sizeof(int));
    int* cursor   = (int*)w;            w += align256(NN * sizeof(int));
    int* bsums    = (int*)w;            w += align256(256 * sizeof(int));
    int* src_csr  = (int*)w;            w += align256((size_t)ET * sizeof(int));
    int* dst_csr  = (int*)w;            w += align256((size_t)ET * sizeof(int));
    float* alpha  = (float*)w;          w += align256((size_t)ET * 2 * sizeof(float));
    float* hA     = (float*)w;          w += align256((size_t)NN * CC * sizeof(float));
    float* hB     = (float*)w;          w += align256((size_t)NN * CC * sizeof(float));

    const int B = 256;
    int nscan = NN + 1;
    int nb = (nscan + SCAN_CHUNK - 1) / SCAN_CHUNK;

    // CSR build (per call; ws is re-poisoned before every launch)
    k_zero<<<(nscan + B - 1) / B, B, 0, stream>>>(rowstart, nscan);
    k_deg<<<(ET + B - 1) / B, B, 0, stream>>>(ei, rowstart, ET);
    k_scan1<<<nb, SCAN_CHUNK, 0, stream>>>(rowstart, bsums, nscan);
    k_scan2<<<1, 64, 0, stream>>>(bsums, nb);
    k_scan3<<<nb, SCAN_CHUNK, 0, stream>>>(rowstart, bsums, nscan);
    k_copy<<<(NN + B - 1) / B, B, 0, stream>>>(rowstart, cursor, NN);
    k_scatter<<<(ET + B - 1) / B, B, 0, stream>>>(ei, cursor, src_csr, dst_csr, ET);

    // features (also initializes d_out = 0.25*x)
    k_init<<<(NN * CC + B - 1) / B, B, 0, stream>>>(x, hA, acc, NN * CC);

    float* hin = hA;
    float* hout = hB;
    for (int l = 0; l < LL; l++) {
        k_alpha<<<(ET * 16 + B - 1) / B, B, 0, stream>>>(
            hin, src_csr, dst_csr, att + (size_t)l * HH * CC, alpha, ET);
        k_agg<<<(NN + 3) / 4, B, 0, stream>>>(
            hin, rowstart, src_csr, alpha, bias + (size_t)l * CC, hout, acc, NN);
        float* t = hin; hin = hout; hout = t;
    }
}

// Round 5
// 322.662 us; speedup vs baseline: 2.2377x; 1.3275x over previous
//
#include <hip/hip_runtime.h>
#include <hip/hip_bf16.h>

#define NN 50000
#define EE 800000
#define ET (EE + NN)   // edges + self loops = 850000
#define CC 64
#define HH 2
#define LL 3
#define SCAN_CHUNK 1024

// ---------------- CSR construction ----------------

__global__ void k_zero(int* p, int n) {
    int i = blockIdx.x * blockDim.x + threadIdx.x;
    if (i < n) p[i] = 0;
}

__global__ void k_deg(const int* __restrict__ ei, int* __restrict__ cnt1, int etot) {
    int e = blockIdx.x * blockDim.x + threadIdx.x;
    if (e < etot) {
        int d = (e < EE) ? ei[EE + e] : (e - EE);
        atomicAdd(&cnt1[d + 1], 1);
    }
}

__global__ __launch_bounds__(SCAN_CHUNK) void k_scan1(int* __restrict__ data,
                                                      int* __restrict__ bsums, int n) {
    __shared__ int tmp[SCAN_CHUNK];
    int i = blockIdx.x * SCAN_CHUNK + threadIdx.x;
    int v = (i < n) ? data[i] : 0;
    tmp[threadIdx.x] = v;
    __syncthreads();
    for (int off = 1; off < SCAN_CHUNK; off <<= 1) {
        int t = (threadIdx.x >= off) ? tmp[threadIdx.x - off] : 0;
        __syncthreads();
        tmp[threadIdx.x] += t;
        __syncthreads();
    }
    if (i < n) data[i] = tmp[threadIdx.x];
    if (threadIdx.x == SCAN_CHUNK - 1) bsums[blockIdx.x] = tmp[SCAN_CHUNK - 1];
}

__global__ void k_scan2(int* bsums, int nb) {
    if (blockIdx.x == 0 && threadIdx.x == 0) {
        int run = 0;
        for (int b = 0; b < nb; b++) { int t = bsums[b]; bsums[b] = run; run += t; }
    }
}

__global__ __launch_bounds__(SCAN_CHUNK) void k_scan3(int* __restrict__ data,
                                                      const int* __restrict__ bsums, int n) {
    int i = blockIdx.x * SCAN_CHUNK + threadIdx.x;
    if (i < n) data[i] += bsums[blockIdx.x];
}

__global__ void k_copy(const int* __restrict__ a, int* __restrict__ b, int n) {
    int i = blockIdx.x * blockDim.x + threadIdx.x;
    if (i < n) b[i] = a[i];
}

// scatter src only — dst is implicit in CSR order
__global__ void k_scatter(const int* __restrict__ ei, int* __restrict__ cursor,
                          int* __restrict__ src_csr, int etot) {
    int e = blockIdx.x * blockDim.x + threadIdx.x;
    if (e < etot) {
        int s, d;
        if (e < EE) { s = ei[e]; d = ei[EE + e]; } else { s = d = e - EE; }
        int pos = atomicAdd(&cursor[d], 1);
        src_csr[pos] = s;
    }
}

// ---------------- acc init (d_out = 0.25*x) ----------------

__global__ void k_init(const float* __restrict__ x, float* __restrict__ acc, int n) {
    int i = blockIdx.x * blockDim.x + threadIdx.x;
    if (i < n) acc[i] = 0.25f * x[i];
}

// ---------------- fused GAT layer: online softmax, one gather per edge ----------------
// wave per node; 4 subgroups x 16 lanes; lane holds channel quad q (c = 4q..4q+3)

__global__ __launch_bounds__(256) void k_gat(const float* __restrict__ h,
                                             const int* __restrict__ rowstart,
                                             const int* __restrict__ src_csr,
                                             const float* __restrict__ att_l,
                                             const float* __restrict__ bias_l,
                                             float* __restrict__ h_out,
                                             float* __restrict__ acc, int n) {
    int wid = threadIdx.x >> 6;
    int lane = threadIdx.x & 63;
    int node = blockIdx.x * 4 + wid;
    if (node >= n) return;
    int sub = lane >> 4, q = lane & 15;
    const float4* h4 = (const float4*)h;
    float4 a0q = ((const float4*)att_l)[q];
    float4 a1q = ((const float4*)att_l)[16 + q];
    float4 hd = h4[(size_t)node * 16 + q];       // dst row, in registers
    int rs = rowstart[node];
    int deg = rowstart[node + 1] - rs;

    float m0 = -1e30f, m1 = -1e30f, s0 = 0.f, s1 = 0.f;
    float4 A0 = make_float4(0.f, 0.f, 0.f, 0.f);
    float4 A1 = make_float4(0.f, 0.f, 0.f, 0.f);

    for (int i = sub; i < deg; i += 4) {
        int s = src_csr[rs + i];
        float4 hv = h4[(size_t)s * 16 + q];
        float vx = hv.x + hd.x, vy = hv.y + hd.y, vz = hv.z + hd.z, vw = hv.w + hd.w;
        vx = fmaxf(vx, 0.f) + 0.2f * fminf(vx, 0.f);
        vy = fmaxf(vy, 0.f) + 0.2f * fminf(vy, 0.f);
        vz = fmaxf(vz, 0.f) + 0.2f * fminf(vz, 0.f);
        vw = fmaxf(vw, 0.f) + 0.2f * fminf(vw, 0.f);
        float a0 = vx * a0q.x + vy * a0q.y + vz * a0q.z + vw * a0q.w;
        float a1 = vx * a1q.x + vy * a1q.y + vz * a1q.z + vw * a1q.w;
#pragma unroll
        for (int m = 8; m; m >>= 1) {            // all 16 lanes get full dot
            a0 += __shfl_xor(a0, m);
            a1 += __shfl_xor(a1, m);
        }
        // online softmax update, head 0
        float nm0 = fmaxf(m0, a0);
        float sc0 = __expf(m0 - nm0);
        float e0  = __expf(a0 - nm0);
        s0 = s0 * sc0 + e0;
        A0.x = A0.x * sc0 + e0 * hv.x;
        A0.y = A0.y * sc0 + e0 * hv.y;
        A0.z = A0.z * sc0 + e0 * hv.z;
        A0.w = A0.w * sc0 + e0 * hv.w;
        m0 = nm0;
        // head 1
        float nm1 = fmaxf(m1, a1);
        float sc1 = __expf(m1 - nm1);
        float e1  = __expf(a1 - nm1);
        s1 = s1 * sc1 + e1;
        A1.x = A1.x * sc1 + e1 * hv.x;
        A1.y = A1.y * sc1 + e1 * hv.y;
        A1.z = A1.z * sc1 + e1 * hv.z;
        A1.w = A1.w * sc1 + e1 * hv.w;
        m1 = nm1;
    }

    // merge the 4 subgroups (flash-style (m,s,A) combine), masks 16 and 32
#pragma unroll
    for (int step = 16; step <= 32; step <<= 1) {
        float om0 = __shfl_xor(m0, step);
        float os0 = __shfl_xor(s0, step);
        float oA0x = __shfl_xor(A0.x, step), oA0y = __shfl_xor(A0.y, step);
        float oA0z = __shfl_xor(A0.z, step), oA0w = __shfl_xor(A0.w, step);
        float nm0 = fmaxf(m0, om0);
        float sc0 = __expf(m0 - nm0), oc0 = __expf(om0 - nm0);
        s0 = s0 * sc0 + os0 * oc0;
        A0.x = A0.x * sc0 + oA0x * oc0;
        A0.y = A0.y * sc0 + oA0y * oc0;
        A0.z = A0.z * sc0 + oA0z * oc0;
        A0.w = A0.w * sc0 + oA0w * oc0;
        m0 = nm0;

        float om1 = __shfl_xor(m1, step);
        float os1 = __shfl_xor(s1, step);
        float oA1x = __shfl_xor(A1.x, step), oA1y = __shfl_xor(A1.y, step);
        float oA1z = __shfl_xor(A1.z, step), oA1w = __shfl_xor(A1.w, step);
        float nm1 = fmaxf(m1, om1);
        float sc1 = __expf(m1 - nm1), oc1 = __expf(om1 - nm1);
        s1 = s1 * sc1 + os1 * oc1;
        A1.x = A1.x * sc1 + oA1x * oc1;
        A1.y = A1.y * sc1 + oA1y * oc1;
        A1.z = A1.z * sc1 + oA1z * oc1;
        A1.w = A1.w * sc1 + oA1w * oc1;
        m1 = nm1;
    }

    if (sub == 0) {
        float inv0 = 0.5f / (s0 + 1e-16f);       // fold mean-over-heads
        float inv1 = 0.5f / (s1 + 1e-16f);
        float4 b4 = ((const float4*)bias_l)[q];
        float4 o;
        o.x = A0.x * inv0 + A1.x * inv1 + b4.x;
        o.y = A0.y * inv0 + A1.y * inv1 + b4.y;
        o.z = A0.z * inv0 + A1.z * inv1 + b4.z;
        o.w = A0.w * inv0 + A1.w * inv1 + b4.w;
        ((float4*)h_out)[(size_t)node * 16 + q] = o;
        float4* accp = (float4*)acc + (size_t)node * 16 + q;
        float4 ac = *accp;
        ac.x += 0.25f * o.x; ac.y += 0.25f * o.y;
        ac.z += 0.25f * o.z; ac.w += 0.25f * o.w;
        *accp = ac;
    }
}

// ---------------- launch ----------------

static inline size_t align256(size_t x) { return (x + 255) & ~(size_t)255; }

extern "C" void kernel_launch(void* const* d_in, const int* in_sizes, int n_in,
                              void* d_out, int out_size, void* d_ws, size_t ws_size,
                              hipStream_t stream) {
    const float* x    = (const float*)d_in[0];
    const int*   ei   = (const int*)d_in[1];
    const float* att  = (const float*)d_in[2];
    const float* bias = (const float*)d_in[3];
    float* acc = (float*)d_out;   // fp32 output; feats-mean accumulated here

    char* w = (char*)d_ws;
    int* rowstart = (int*)w;            w += align256((NN + 1) * sizeof(int));
    int* cursor   = (int*)w;            w += align256(NN * sizeof(int));
    int* bsums    = (int*)w;            w += align256(256 * sizeof(int));
    int* src_csr  = (int*)w;            w += align256((size_t)ET * sizeof(int));
    float* hA     = (float*)w;          w += align256((size_t)NN * CC * sizeof(float));
    float* hB     = (float*)w;          w += align256((size_t)NN * CC * sizeof(float));

    const int B = 256;
    int nscan = NN + 1;
    int nb = (nscan + SCAN_CHUNK - 1) / SCAN_CHUNK;

    // CSR build (per call; ws is re-poisoned before every launch)
    k_zero<<<(nscan + B - 1) / B, B, 0, stream>>>(rowstart, nscan);
    k_deg<<<(ET + B - 1) / B, B, 0, stream>>>(ei, rowstart, ET);
    k_scan1<<<nb, SCAN_CHUNK, 0, stream>>>(rowstart, bsums, nscan);
    k_scan2<<<1, 64, 0, stream>>>(bsums, nb);
    k_scan3<<<nb, SCAN_CHUNK, 0, stream>>>(rowstart, bsums, nscan);
    k_copy<<<(NN + B - 1) / B, B, 0, stream>>>(rowstart, cursor, NN);
    k_scatter<<<(ET + B - 1) / B, B, 0, stream>>>(ei, cursor, src_csr, ET);

    // d_out = 0.25*x
    k_init<<<(NN * CC + B - 1) / B, B, 0, stream>>>(x, acc, NN * CC);

    // 3 fused GAT layers; layer 0 reads x directly
    const float* hin = x;
    float* houts[LL] = {hA, hB, hA};
    for (int l = 0; l < LL; l++) {
        k_gat<<<(NN + 3) / 4, B, 0, stream>>>(
            hin, rowstart, src_csr, att + (size_t)l * HH * CC,
            bias + (size_t)l * CC, houts[l], acc, NN);
        hin = houts[l];
    }
}